// Round 17
// baseline (392.104 us; speedup 1.0000x reference)
//
#include <hip/hip_runtime.h>
#include <hip/hip_bf16.h>
#include <cstdint>
#include <cstddef>

#define EPS 1e-5f
#define BB 4096
#define TT 64
#define NBLK 2
#define MROWS (BB * TT)

typedef unsigned short ushort_t;
typedef __attribute__((ext_vector_type(8))) short short8;
typedef __attribute__((ext_vector_type(4))) float floatx4;

__device__ __forceinline__ ushort_t f2b(float f) {
    __hip_bfloat16 h = __float2bfloat16(f);
    return *reinterpret_cast<ushort_t*>(&h);
}
__device__ __forceinline__ float tanh_fast(float z) {
    return 1.f - 2.f / (__expf(2.f * z) + 1.f);
}
// v_rcp_f32: ~1ulp fp32 error (2^-22) — used ONLY in the scan nonlinearity.
__device__ __forceinline__ float rcp_f(float x) {
    return __builtin_amdgcn_rcpf(x);
}
// LDS-only barrier: omits vmcnt drain on purpose.
__device__ __forceinline__ void lds_barrier() {
    asm volatile("s_waitcnt lgkmcnt(0)\n\ts_barrier" ::: "memory");
}
// wave-local DS drain (scan-proven pattern; NOT a barrier)
__device__ __forceinline__ void ds_wait() {
    asm volatile("s_waitcnt lgkmcnt(0)" ::: "memory");
}

// DPP row_ror cyclic-add reduction over 16 lanes (pure VALU; r4-proven).
template <int CTRL>
__device__ __forceinline__ float ror_add(float v) {
    int r = __builtin_amdgcn_update_dpp(
        0, __builtin_bit_cast(int, v), CTRL, 0xf, 0xf, false);
    return v + __builtin_bit_cast(float, r);
}
__device__ __forceinline__ float red16(float v) {
    v = ror_add<0x121>(v);  // ror 1
    v = ror_add<0x122>(v);  // ror 2
    v = ror_add<0x124>(v);  // ror 4
    v = ror_add<0x128>(v);  // ror 8
    return v;
}

// ---------------- all weight converts in one launch ----------------
// r22: source-linear indexing — reads fully coalesced.
__global__ __launch_bounds__(256) void k_cvtall(
    const float* __restrict__ Wg, const float* __restrict__ W1,
    const float* __restrict__ W2, ushort_t* __restrict__ Wgt,
    ushort_t* __restrict__ W1t, ushort_t* __restrict__ W2t) {
    int idx = blockIdx.x * 256 + threadIdx.x;
    if (idx < 2 * 512 * 128) {
        int blk = idx >> 16, r = idx & 65535;
        int k = r >> 9, n = r & 511;
        Wgt[(size_t)blk * 65536 + n * 128 + k] = f2b(Wg[idx]);
    } else if (idx < 2 * 512 * 128 + 2 * 128 * 128) {
        int i2 = idx - 2 * 512 * 128;
        int blk = i2 >> 14, r = i2 & 16383;
        int k = r >> 7, n = r & 127;
        W1t[(size_t)blk * 16384 + n * 128 + k] = f2b(W1[i2]);
    } else {
        int i2 = idx - (2 * 512 * 128 + 2 * 128 * 128);
        int blk = i2 >> 14, r = i2 & 16383;
        int k = r >> 7, n = r & 127;
        W2t[(size_t)blk * 16384 + n * 128 + k] = f2b(W2[i2]);
    }
}

// ---------------- producer/consumer fused gate-GEMM + per-head sLSTM scan ----------------
// r16-verbatim (harness-verified 330us / absmax 0.03125). Do not touch.
template <bool EMBED, bool LASTONLY>
__global__ __launch_bounds__(512, 2) void k_gslstm(
    float* __restrict__ h, const float* __restrict__ x,
    const float* __restrict__ w_in, const float* __restrict__ b_in,
    const ushort_t* __restrict__ Wgt, const float* __restrict__ bg,
    const float* __restrict__ Rg,
    const float* __restrict__ ln1g, const float* __restrict__ ln1b,
    const float* __restrict__ gng, const float* __restrict__ gnb) {
    __shared__ float xg_ring[2][512][16];      // 65536 B (rotated cols)
    __shared__ ushort_t Afrag[2][16][136];     // 8704 B, LN1 output bf16 [m][k]
    __shared__ ushort_t tpose[4][16][40];      // 5120 B

    const int tid = threadIdx.x;
    const int lane = tid & 63;
    const int wave = tid >> 6;   // 0..7
    const int q = lane >> 4;     // 0..3
    const int ml = lane & 15;
    const int b0 = blockIdx.x * 16;
    const int xc = ((q + (ml >> 1)) & 3) * 4;  // rotated xg column

    if (wave < 4) {
        // ================== PRODUCER ==================
        const int p = wave;
        const int row = p * 4 + q;
        short8 WB[4][8];
#pragma unroll
        for (int ks = 0; ks < 4; ++ks)
#pragma unroll
            for (int s = 0; s < 8; ++s)
                WB[ks][s] = *(const short8*)(Wgt +
                    ((size_t)(p * 128 + s * 16 + ml) * 128 + ks * 32 + q * 8));
        float biasv[8];
#pragma unroll
        for (int s = 0; s < 8; ++s) biasv[s] = bg[p * 128 + s * 16 + ml];

        const float4 Lg0 = *(const float4*)(ln1g + ml * 8);
        const float4 Lg1 = *(const float4*)(ln1g + ml * 8 + 4);
        const float4 Lb0 = *(const float4*)(ln1b + ml * 8);
        const float4 Lb1 = *(const float4*)(ln1b + ml * 8 + 4);
        float4 W00{}, W01{}, W10{}, W11{}, W20{}, W21{}, BE0{}, BE1{};
        if (EMBED) {
            W00 = *(const float4*)(w_in + 0 * 128 + ml * 8);
            W01 = *(const float4*)(w_in + 0 * 128 + ml * 8 + 4);
            W10 = *(const float4*)(w_in + 1 * 128 + ml * 8);
            W11 = *(const float4*)(w_in + 1 * 128 + ml * 8 + 4);
            W20 = *(const float4*)(w_in + 2 * 128 + ml * 8);
            W21 = *(const float4*)(w_in + 2 * 128 + ml * 8 + 4);
            BE0 = *(const float4*)(b_in + ml * 8);
            BE1 = *(const float4*)(b_in + ml * 8 + 4);
        }

        auto issue_in = [&](int tt, float4& A, float4& B) {
            const float4* hp =
                (const float4*)(h + ((size_t)(b0 + row) * TT + tt) * 128 + ml * 8);
            A = hp[0]; B = hp[1];
        };
        auto issue_x = [&](int tt, float& x0, float& x1, float& x2) {
            const float* xp = x + ((size_t)(b0 + row) * TT + tt) * 3;
            x0 = xp[0]; x1 = xp[1]; x2 = xp[2];
        };
        auto embed_v = [&](float x0, float x1, float x2, float* v) {
            const float w0[8] = {W00.x, W00.y, W00.z, W00.w, W01.x, W01.y, W01.z, W01.w};
            const float w1[8] = {W10.x, W10.y, W10.z, W10.w, W11.x, W11.y, W11.z, W11.w};
            const float w2[8] = {W20.x, W20.y, W20.z, W20.w, W21.x, W21.y, W21.z, W21.w};
            const float be[8] = {BE0.x, BE0.y, BE0.z, BE0.w, BE1.x, BE1.y, BE1.z, BE1.w};
#pragma unroll
            for (int j = 0; j < 8; ++j)
                v[j] = x0 * w0[j] + x1 * w1[j] + x2 * w2[j] + be[j];
        };
        auto ln_stage = [&](const float* v, int aslot) {
            float s = 0.f, ss = 0.f;
#pragma unroll
            for (int j = 0; j < 8; ++j) { s += v[j]; ss += v[j] * v[j]; }
            s = red16(s);
            ss = red16(ss);
            float mu = s * (1.f / 128.f);
            float rstd = rsqrtf(ss * (1.f / 128.f) - mu * mu + EPS);
            const float gg[8] = {Lg0.x, Lg0.y, Lg0.z, Lg0.w, Lg1.x, Lg1.y, Lg1.z, Lg1.w};
            const float bbv[8] = {Lb0.x, Lb0.y, Lb0.z, Lb0.w, Lb1.x, Lb1.y, Lb1.z, Lb1.w};
            ushort_t pk[8];
#pragma unroll
            for (int j = 0; j < 8; ++j)
                pk[j] = f2b((v[j] - mu) * rstd * gg[j] + bbv[j]);
            *(short8*)&Afrag[aslot][row][ml * 8] = *(const short8*)pk;
        };
        auto gemm_stage = [&](int slot) {
            short8 af[4];
#pragma unroll
            for (int ks = 0; ks < 4; ++ks)
                af[ks] = *(const short8*)&Afrag[slot][ml][ks * 32 + q * 8];
            floatx4 acc[8];
#pragma unroll
            for (int s = 0; s < 8; ++s) {
                float b = biasv[s];
                acc[s] = (floatx4){b, b, b, b};
            }
#pragma unroll
            for (int ks = 0; ks < 4; ++ks)
#pragma unroll
                for (int s = 0; s < 8; ++s)
                    acc[s] = __builtin_amdgcn_mfma_f32_16x16x32_bf16(
                        af[ks], WB[ks][s], acc[s], 0, 0, 0);
#pragma unroll
            for (int s = 0; s < 8; ++s)
                *(floatx4*)&xg_ring[slot][p * 128 + s * 16 + ml][xc] = acc[s];
        };

        float4 pA0, pA1, pB0, pB1;
        float px0 = 0.f, px1 = 0.f, px2 = 0.f, qx0 = 0.f, qx1 = 0.f, qx2 = 0.f;
        {
            float v[8];
            if (EMBED) {
                float a0, a1, a2, d0, d1, d2v;
                issue_x(0, a0, a1, a2);
                issue_x(1, d0, d1, d2v);
                issue_x(2, px0, px1, px2);
                embed_v(a0, a1, a2, v);  ln_stage(v, 0);
                embed_v(d0, d1, d2v, v); ln_stage(v, 1);
            } else {
                float4 a0, a1, d0, d1;
                issue_in(0, a0, a1);
                issue_in(1, d0, d1);
                issue_in(2, pA0, pA1);
                *(float4*)v = a0; *(float4*)(v + 4) = a1; ln_stage(v, 0);
                *(float4*)v = d0; *(float4*)(v + 4) = d1; ln_stage(v, 1);
            }
        }
        lds_barrier();
        gemm_stage(0);  // xg(0)
        lds_barrier();

#pragma unroll 1
        for (int t = 0; t < TT; t += 2) {
            if (t + 3 < TT) {
                if (EMBED) issue_x(t + 3, qx0, qx1, qx2);
                else       issue_in(t + 3, pB0, pB1);
            }
            gemm_stage((t + 1) & 1);
            if (t + 2 < TT) {
                float v[8];
                if (EMBED) embed_v(px0, px1, px2, v);
                else { *(float4*)v = pA0; *(float4*)(v + 4) = pA1; }
                ln_stage(v, t & 1);
            }
            lds_barrier();
            if (t + 4 < TT) {
                if (EMBED) issue_x(t + 4, px0, px1, px2);
                else       issue_in(t + 4, pA0, pA1);
            }
            if (t + 2 < TT) gemm_stage(t & 1);
            if (t + 3 < TT) {
                float v[8];
                if (EMBED) embed_v(qx0, qx1, qx2, v);
                else { *(float4*)v = pB0; *(float4*)(v + 4) = pB1; }
                ln_stage(v, (t + 1) & 1);
            }
            lds_barrier();
        }
    } else {
        // ================== SCAN (one head per wave) ==================
        __builtin_amdgcn_s_setprio(1);
        const int hd = wave - 4;
        short8 RB[4][2];
#pragma unroll
        for (int g = 0; g < 4; ++g)
#pragma unroll
            for (int d2 = 0; d2 < 2; ++d2) {
                ushort_t tmp[8];
#pragma unroll
                for (int j = 0; j < 8; ++j)
                    tmp[j] = f2b(Rg[(size_t)g * 4096 + hd * 1024 +
                                    (q * 8 + j) * 32 + d2 * 16 + ml]);
                RB[g][d2] = *(const short8*)tmp;
            }
        const float gng0 = gng[hd * 32 + ml], gng1 = gng[hd * 32 + 16 + ml];
        const float gnb0 = gnb[hd * 32 + ml], gnb1 = gnb[hd * 32 + 16 + ml];
        float we[3][2], beh[2];
        if (EMBED) {
#pragma unroll
            for (int d2 = 0; d2 < 2; ++d2) {
#pragma unroll
                for (int c = 0; c < 3; ++c)
                    we[c][d2] = w_in[c * 128 + hd * 32 + d2 * 16 + ml];
                beh[d2] = b_in[hd * 32 + d2 * 16 + ml];
            }
        }
        float cst[8], nst[8], mst[8];
#pragma unroll
        for (int i = 0; i < 8; ++i) { cst[i] = 0.f; nst[i] = 0.f; mst[i] = 0.f; }
        {
            ushort_t* tp = &tpose[hd][0][0];
            for (int i = lane; i < 16 * 40; i += 64) tp[i] = 0;
        }

        auto scan_iter = [&](int t) {
            const bool doGN = (!LASTONLY || t == TT - 1);
            float xv[4][3];    // EMBED path
            float hg[4][2];    // global-h path (LASTONLY)
            if (doGN) {
                if (EMBED) {
#pragma unroll
                    for (int r = 0; r < 4; ++r) {
                        const float* xp =
                            x + ((size_t)(b0 + q * 4 + r) * TT + t) * 3;
                        xv[r][0] = xp[0]; xv[r][1] = xp[1]; xv[r][2] = xp[2];
                    }
                } else {
#pragma unroll
                    for (int r = 0; r < 4; ++r)
#pragma unroll
                        for (int d2 = 0; d2 < 2; ++d2)
                            hg[r][d2] = h[((size_t)(b0 + q * 4 + r) * TT + t) * 128 +
                                          hd * 32 + d2 * 16 + ml];
                }
            }
            short8 h8 = *(const short8*)&tpose[hd][ml][q * 8];
            floatx4 acc[4][2];
#pragma unroll
            for (int g = 0; g < 4; ++g)
#pragma unroll
                for (int d2 = 0; d2 < 2; ++d2)
                    acc[g][d2] = *(const floatx4*)
                        &xg_ring[t & 1][g * 128 + hd * 32 + d2 * 16 + ml][xc];
#pragma unroll
            for (int g = 0; g < 4; ++g)
#pragma unroll
                for (int d2 = 0; d2 < 2; ++d2)
                    acc[g][d2] = __builtin_amdgcn_mfma_f32_16x16x32_bf16(
                        h8, RB[g][d2], acc[g][d2], 0, 0, 0);
            float hv[2][4];
#pragma unroll
            for (int d2 = 0; d2 < 2; ++d2)
#pragma unroll
                for (int r = 0; r < 4; ++r) {
                    const int si = d2 * 4 + r;
                    float it = acc[0][d2][r], ft = acc[1][d2][r];
                    float zt = acc[2][d2][r], ot = acc[3][d2][r];
                    float mn = fmaxf(ft + mst[si], it);
                    float iv = __expf(it - mn);
                    float fv = __expf(ft + mst[si] - mn);
                    float e2 = __expf(2.f * zt);
                    float th = 1.f - 2.f * rcp_f(e2 + 1.f);
                    float cn = fv * cst[si] + iv * th;
                    float nn = fv * nst[si] + iv;
                    float eo = __expf(-ot);
                    hv[d2][r] = cn * rcp_f(nn + nn * eo);
                    cst[si] = cn; nst[si] = nn; mst[si] = mn;
                }
#pragma unroll
            for (int d2 = 0; d2 < 2; ++d2)
#pragma unroll
                for (int r = 0; r < 4; ++r)
                    tpose[hd][q * 4 + r][d2 * 16 + ml] = f2b(hv[d2][r]);
            if (doGN) {
                float hinv[4][2];
#pragma unroll
                for (int r = 0; r < 4; ++r)
#pragma unroll
                    for (int d2 = 0; d2 < 2; ++d2) {
                        if (EMBED)
                            hinv[r][d2] = xv[r][0] * we[0][d2] +
                                          xv[r][1] * we[1][d2] +
                                          xv[r][2] * we[2][d2] + beh[d2];
                        else
                            hinv[r][d2] = hg[r][d2];
                    }
                float s[4], ss[4];
#pragma unroll
                for (int r = 0; r < 4; ++r) {
                    s[r] = hv[0][r] + hv[1][r];
                    ss[r] = hv[0][r] * hv[0][r] + hv[1][r] * hv[1][r];
                }
#pragma unroll
                for (int r = 0; r < 4; ++r) {
                    s[r] = red16(s[r]);
                    ss[r] = red16(ss[r]);
                }
#pragma unroll
                for (int r = 0; r < 4; ++r) {
                    float mu = s[r] * (1.f / 32.f);
                    float rstd = rsqrtf(ss[r] * (1.f / 32.f) - mu * mu + EPS);
#pragma unroll
                    for (int d2 = 0; d2 < 2; ++d2) {
                        float gv = d2 ? gng1 : gng0;
                        float bv = d2 ? gnb1 : gnb0;
                        h[((size_t)(b0 + q * 4 + r) * TT + t) * 128 +
                          hd * 32 + d2 * 16 + ml] =
                            hinv[r][d2] + (hv[d2][r] - mu) * rstd * gv + bv;
                    }
                }
            }
        };

        lds_barrier();
        lds_barrier();
#pragma unroll 1
        for (int t = 0; t < TT; t += 2) {
            scan_iter(t);
            lds_barrier();
            scan_iter(t + 1);
            lds_barrier();
        }
    }
}

// ---------------- barrier-free wave-local FFN: h += gelu(LN2(h) @ W1) @ W2 ----------
// ROUND-27: replaces the barrier-lockstep k_ffn_pipe (~85us, 4 s_barrier/tile).
// Each WAVE independently owns one 16-row tile: A-fragments load DIRECTLY from
// global in MFMA layout (lane (q,ml) = row ml, k-chunk q*8 — per instruction:
// 16 rows x contiguous chunks, sector-clean); LN2 stats via shfl_xor(16/32)
// across the 4 q-lanes of each row; W1/W2 fragments streamed from L2 per
// col-tile; the two transposes (gelu->A2-frag, C->row-major) go through a
// WAVE-PRIVATE LDS tile with lgkmcnt-only ordering (the scan's proven tpose
// pattern). Residual = the raw registers (they ARE h). ZERO s_barrier.
// grid = MROWS/64 wgs x 256 thr (4 waves/wg). gelu/MFMA math verbatim.
__global__ __launch_bounds__(256) void k_ffn_wave(
    float* __restrict__ h, const ushort_t* __restrict__ W1t,
    const ushort_t* __restrict__ W2t,
    const float* __restrict__ lng, const float* __restrict__ lnb) {
    // per-wave union: bf16 T1-transpose [16][136] (4352B) / f32 out [16][132] (8448B)
    __shared__ __align__(16) char LDSU[4][16 * 132 * 4];
    const int tid = threadIdx.x;
    const int lane = tid & 63, wave = tid >> 6;
    const int q = lane >> 4, ml = lane & 15;
    auto tp = (ushort_t(*)[136])(LDSU[wave]);
    auto ot = (float(*)[132])(LDSU[wave]);
    const size_t row0 = (size_t)(blockIdx.x * 4 + wave) * 16;

    // ---- raw h (residual) + LN2 stats ----
    float* hp = h + (row0 + ml) * 128;
    float4 raw[8];
#pragma unroll
    for (int ks = 0; ks < 4; ++ks) {
        raw[2 * ks]     = *(const float4*)(hp + ks * 32 + q * 8);
        raw[2 * ks + 1] = *(const float4*)(hp + ks * 32 + q * 8 + 4);
    }
    float s = 0.f, ss = 0.f;
#pragma unroll
    for (int i = 0; i < 8; ++i) {
        float4 v = raw[i];
        s += v.x + v.y + v.z + v.w;
        ss += v.x * v.x + v.y * v.y + v.z * v.z + v.w * v.w;
    }
    s += __shfl_xor(s, 16); ss += __shfl_xor(ss, 16);
    s += __shfl_xor(s, 32); ss += __shfl_xor(ss, 32);
    float mu = s * (1.f / 128.f);
    float rstd = rsqrtf(ss * (1.f / 128.f) - mu * mu + EPS);

    // ---- A-frag (bf16) in MFMA layout, normalized in-register ----
    short8 af[4];
#pragma unroll
    for (int ks = 0; ks < 4; ++ks) {
        int c0 = ks * 32 + q * 8;
        float4 g0 = *(const float4*)(lng + c0);
        float4 g1 = *(const float4*)(lng + c0 + 4);
        float4 b0 = *(const float4*)(lnb + c0);
        float4 b1 = *(const float4*)(lnb + c0 + 4);
        float4 a = raw[2 * ks], b = raw[2 * ks + 1];
        ushort_t p[8];
        p[0] = f2b((a.x - mu) * rstd * g0.x + b0.x);
        p[1] = f2b((a.y - mu) * rstd * g0.y + b0.y);
        p[2] = f2b((a.z - mu) * rstd * g0.z + b0.z);
        p[3] = f2b((a.w - mu) * rstd * g0.w + b0.w);
        p[4] = f2b((b.x - mu) * rstd * g1.x + b1.x);
        p[5] = f2b((b.y - mu) * rstd * g1.y + b1.y);
        p[6] = f2b((b.z - mu) * rstd * g1.z + b1.z);
        p[7] = f2b((b.w - mu) * rstd * g1.w + b1.w);
        af[ks] = *(const short8*)p;
    }

    // ---- GEMM1 over 8 col-tiles + gelu -> tp (bf16 transpose) ----
#pragma unroll
    for (int cn = 0; cn < 8; ++cn) {
        short8 WB[4];
#pragma unroll
        for (int ks = 0; ks < 4; ++ks)
            WB[ks] = *(const short8*)(W1t +
                ((size_t)(cn * 16 + ml) * 128 + ks * 32 + q * 8));
        floatx4 acc = (floatx4)0.f;
#pragma unroll
        for (int ks = 0; ks < 4; ++ks)
            acc = __builtin_amdgcn_mfma_f32_16x16x32_bf16(af[ks], WB[ks], acc, 0, 0, 0);
#pragma unroll
        for (int rr = 0; rr < 4; ++rr) {
            float v = acc[rr];
            float u = 0.7978845608028654f * (v + 0.044715f * v * v * v);
            float gv = 0.5f * v * (1.f + tanh_fast(u));
            tp[q * 4 + rr][cn * 16 + ml] = f2b(gv);
        }
    }
    ds_wait();  // wave-local: all 64 lanes' tp writes drained (same-wave DS in-order)

    // ---- A2-frag from tp ----
    short8 a2[4];
#pragma unroll
    for (int ks = 0; ks < 4; ++ks)
        a2[ks] = *(const short8*)&tp[ml][ks * 32 + q * 8];

    // ---- GEMM2 over 8 col-tiles -> ot (f32 transpose) ----
#pragma unroll
    for (int cn = 0; cn < 8; ++cn) {
        short8 WB[4];
#pragma unroll
        for (int ks = 0; ks < 4; ++ks)
            WB[ks] = *(const short8*)(W2t +
                ((size_t)(cn * 16 + ml) * 128 + ks * 32 + q * 8));
        floatx4 acc = (floatx4)0.f;
#pragma unroll
        for (int ks = 0; ks < 4; ++ks)
            acc = __builtin_amdgcn_mfma_f32_16x16x32_bf16(a2[ks], WB[ks], acc, 0, 0, 0);
#pragma unroll
        for (int rr = 0; rr < 4; ++rr)
            ot[q * 4 + rr][cn * 16 + ml] = acc[rr];
        // NOTE: ot aliases tp, but per-wave DS ops are in-order: all a2 reads
        // were issued before these writes.
    }
    ds_wait();  // ot complete

    // ---- row-major read + residual (raw regs) + coalesced store ----
#pragma unroll
    for (int ks = 0; ks < 4; ++ks) {
        float4 o0 = *(const float4*)&ot[ml][ks * 32 + q * 8];
        float4 o1 = *(const float4*)&ot[ml][ks * 32 + q * 8 + 4];
        float4 a = raw[2 * ks], b = raw[2 * ks + 1];
        o0.x += a.x; o0.y += a.y; o0.z += a.z; o0.w += a.w;
        o1.x += b.x; o1.y += b.y; o1.z += b.z; o1.w += b.w;
        *(float4*)(hp + ks * 32 + q * 8) = o0;
        *(float4*)(hp + ks * 32 + q * 8 + 4) = o1;
    }
}

// ---------------- fused tail: FFN(t=T-1 rows) + final LN + matvec ----------------
// r14-verbatim (harness-verified).
__global__ __launch_bounds__(256, 6) void k_tail(
    const float* __restrict__ h, const ushort_t* __restrict__ W1t,
    const ushort_t* __restrict__ W2t,
    const float* __restrict__ lng, const float* __restrict__ lnb,
    const float* __restrict__ lnfg, const float* __restrict__ lnfb,
    const float* __restrict__ w_out, const float* __restrict__ b_out,
    float* __restrict__ out) {
    __shared__ __align__(16) char U[32 * 136 * 2 * 2];  // As+T1 (bf16) ∪ F (f32)
    auto As = (ushort_t(*)[136])U;
    auto T1 = (ushort_t(*)[136])(U + 32 * 136 * 2);
    auto F = (float(*)[136])U;
    int tid = threadIdx.x;
    int lane = tid & 63, wave = tid >> 6;
    int q = lane >> 4, ml = lane & 15;
    int wn = wave * 32;
    size_t row0 = (size_t)blockIdx.x * 32;

    short8 W1B[2][4];
#pragma unroll
    for (int jn = 0; jn < 2; ++jn)
#pragma unroll
        for (int ks = 0; ks < 4; ++ks)
            W1B[jn][ks] = *(const short8*)(W1t +
                ((size_t)(wn + jn * 16 + ml) * 128 + ks * 32 + q * 8));

    int r = tid >> 3, qd = tid & 7;
    size_t grow = (row0 + r) * TT + (TT - 1);
    const float* hrow = h + grow * 128 + qd * 16;
    float s = 0.f, ss = 0.f;
#pragma unroll
    for (int k = 0; k < 4; ++k) {
        float4 v = ((const float4*)hrow)[k];
        s += v.x + v.y + v.z + v.w;
        ss += v.x * v.x + v.y * v.y + v.z * v.z + v.w * v.w;
    }
    s += __shfl_xor(s, 1); ss += __shfl_xor(ss, 1);
    s += __shfl_xor(s, 2); ss += __shfl_xor(ss, 2);
    s += __shfl_xor(s, 4); ss += __shfl_xor(ss, 4);
    float mu = s * (1.f / 128.f);
    float rstd = rsqrtf(ss * (1.f / 128.f) - mu * mu + EPS);
#pragma unroll
    for (int kk = 0; kk < 2; ++kk) {
        float4 a = ((const float4*)hrow)[2 * kk];
        float4 b = ((const float4*)hrow)[2 * kk + 1];
        int c0 = qd * 16 + kk * 8;
        float4 g0 = *(const float4*)(lng + c0);
        float4 g1 = *(const float4*)(lng + c0 + 4);
        float4 b0 = *(const float4*)(lnb + c0);
        float4 b1 = *(const float4*)(lnb + c0 + 4);
        ushort_t p[8];
        p[0] = f2b((a.x - mu) * rstd * g0.x + b0.x);
        p[1] = f2b((a.y - mu) * rstd * g0.y + b0.y);
        p[2] = f2b((a.z - mu) * rstd * g0.z + b0.z);
        p[3] = f2b((a.w - mu) * rstd * g0.w + b0.w);
        p[4] = f2b((b.x - mu) * rstd * g1.x + b1.x);
        p[5] = f2b((b.y - mu) * rstd * g1.y + b1.y);
        p[6] = f2b((b.z - mu) * rstd * g1.z + b1.z);
        p[7] = f2b((b.w - mu) * rstd * g1.w + b1.w);
        *(short8*)&As[r][c0] = *(const short8*)p;
    }
    lds_barrier();  // b1: As ready

    floatx4 acc[2][2];
#pragma unroll
    for (int i = 0; i < 2; ++i)
#pragma unroll
        for (int j = 0; j < 2; ++j) acc[i][j] = (floatx4)0.f;
#pragma unroll
    for (int ks = 0; ks < 4; ++ks) {
        short8 af[2];
#pragma unroll
        for (int im = 0; im < 2; ++im)
            af[im] = *(const short8*)&As[im * 16 + ml][ks * 32 + q * 8];
#pragma unroll
        for (int im = 0; im < 2; ++im)
#pragma unroll
            for (int jn = 0; jn < 2; ++jn)
                acc[im][jn] = __builtin_amdgcn_mfma_f32_16x16x32_bf16(
                    af[im], W1B[jn][ks], acc[im][jn], 0, 0, 0);
    }
#pragma unroll
    for (int im = 0; im < 2; ++im)
#pragma unroll
        for (int jn = 0; jn < 2; ++jn)
#pragma unroll
            for (int rr = 0; rr < 4; ++rr) {
                float v = acc[im][jn][rr];
                float u = 0.7978845608028654f * (v + 0.044715f * v * v * v);
                float gv = 0.5f * v * (1.f + tanh_fast(u));
                T1[im * 16 + q * 4 + rr][wn + jn * 16 + ml] = f2b(gv);
            }
    short8 W2B[2][4];
#pragma unroll
    for (int jn = 0; jn < 2; ++jn)
#pragma unroll
        for (int ks = 0; ks < 4; ++ks)
            W2B[jn][ks] = *(const short8*)(W2t +
                ((size_t)(wn + jn * 16 + ml) * 128 + ks * 32 + q * 8));
    lds_barrier();  // b2: T1 ready (As dead hereafter)

    float rres[2][2][4];
#pragma unroll
    for (int im = 0; im < 2; ++im)
#pragma unroll
        for (int jn = 0; jn < 2; ++jn)
#pragma unroll
            for (int rr = 0; rr < 4; ++rr) {
                int rloc = im * 16 + q * 4 + rr;
                rres[im][jn][rr] = h[((row0 + rloc) * TT + (TT - 1)) * 128 +
                                     wn + jn * 16 + ml];
            }
#pragma unroll
    for (int i = 0; i < 2; ++i)
#pragma unroll
        for (int j = 0; j < 2; ++j) acc[i][j] = (floatx4)0.f;
#pragma unroll
    for (int ks = 0; ks < 4; ++ks) {
        short8 af[2];
#pragma unroll
        for (int im = 0; im < 2; ++im)
            af[im] = *(const short8*)&T1[im * 16 + ml][ks * 32 + q * 8];
#pragma unroll
        for (int im = 0; im < 2; ++im)
#pragma unroll
            for (int jn = 0; jn < 2; ++jn)
                acc[im][jn] = __builtin_amdgcn_mfma_f32_16x16x32_bf16(
                    af[im], W2B[jn][ks], acc[im][jn], 0, 0, 0);
    }
    lds_barrier();  // b3: T1 consumed -> U reusable as F
#pragma unroll
    for (int im = 0; im < 2; ++im)
#pragma unroll
        for (int jn = 0; jn < 2; ++jn)
#pragma unroll
            for (int rr = 0; rr < 4; ++rr) {
                int rloc = im * 16 + q * 4 + rr;
                F[rloc][wn + jn * 16 + ml] = rres[im][jn][rr] + acc[im][jn][rr];
            }
    lds_barrier();  // b4: F ready

    float4 fv[4];
#pragma unroll
    for (int k = 0; k < 4; ++k)
        fv[k] = *(const float4*)&F[r][qd * 16 + k * 4];
    float s2 = 0.f, ss2 = 0.f;
#pragma unroll
    for (int k = 0; k < 4; ++k) {
        float4 v = fv[k];
        s2 += v.x + v.y + v.z + v.w;
        ss2 += v.x * v.x + v.y * v.y + v.z * v.z + v.w * v.w;
    }
    s2 += __shfl_xor(s2, 1); ss2 += __shfl_xor(ss2, 1);
    s2 += __shfl_xor(s2, 2); ss2 += __shfl_xor(ss2, 2);
    s2 += __shfl_xor(s2, 4); ss2 += __shfl_xor(ss2, 4);
    float mu2 = s2 * (1.f / 128.f);
    float rstd2 = rsqrtf(ss2 * (1.f / 128.f) - mu2 * mu2 + EPS);
    float dot = 0.f;
#pragma unroll
    for (int k = 0; k < 4; ++k) {
        int c0 = qd * 16 + k * 4;
        float4 g = *(const float4*)(lnfg + c0);
        float4 bb = *(const float4*)(lnfb + c0);
        float4 w = *(const float4*)(w_out + c0);
        dot += ((fv[k].x - mu2) * rstd2 * g.x + bb.x) * w.x +
               ((fv[k].y - mu2) * rstd2 * g.y + bb.y) * w.y +
               ((fv[k].z - mu2) * rstd2 * g.z + bb.z) * w.z +
               ((fv[k].w - mu2) * rstd2 * g.w + bb.w) * w.w;
    }
    dot += __shfl_xor(dot, 1);
    dot += __shfl_xor(dot, 2);
    dot += __shfl_xor(dot, 4);
    if (qd == 0) out[row0 + r] = dot + b_out[0];
}

extern "C" void kernel_launch(void* const* d_in, const int* in_sizes, int n_in,
                              void* d_out, int out_size, void* d_ws, size_t ws_size,
                              hipStream_t stream) {
    const float* x    = (const float*)d_in[0];
    const float* w_in = (const float*)d_in[1];
    const float* b_in = (const float*)d_in[2];
    const float* ln1g = (const float*)d_in[3];
    const float* ln1b = (const float*)d_in[4];
    const float* Wg   = (const float*)d_in[5];
    const float* bg   = (const float*)d_in[6];
    const float* Rg   = (const float*)d_in[7];
    const float* gng  = (const float*)d_in[8];
    const float* gnb  = (const float*)d_in[9];
    const float* ln2g = (const float*)d_in[10];
    const float* ln2b = (const float*)d_in[11];
    const float* W1   = (const float*)d_in[12];
    const float* W2   = (const float*)d_in[13];
    const float* lnfg = (const float*)d_in[14];
    const float* lnfb = (const float*)d_in[15];
    const float* wout = (const float*)d_in[16];
    const float* bout = (const float*)d_in[17];
    float* out = (float*)d_out;

    float* h = (float*)d_ws;
    ushort_t* Wgt = (ushort_t*)(h + (size_t)MROWS * 128);
    ushort_t* W1t = Wgt + 2 * 512 * 128;
    ushort_t* W2t = W1t + 2 * 128 * 128;

    k_cvtall<<<(2 * 512 * 128 + 4 * 128 * 128) / 256, 256, 0, stream>>>(
        Wg, W1, W2, Wgt, W1t, W2t);

    k_gslstm<true, false><<<BB / 16, 512, 0, stream>>>(
        h, x, w_in, b_in, Wgt, bg, Rg, ln1g, ln1b, gng, gnb);
    k_ffn_wave<<<MROWS / 64, 256, 0, stream>>>(h, W1t, W2t, ln2g, ln2b);
    k_gslstm<false, true><<<BB / 16, 512, 0, stream>>>(
        h, nullptr, nullptr, nullptr, Wgt + (size_t)512 * 128, bg + 512,
        Rg + (size_t)16384, ln1g + 128, ln1b + 128, gng + 128, gnb + 128);
    k_tail<<<BB / 32, 256, 0, stream>>>(h, W1t + 16384, W2t + 16384,
                                        ln2g + 128, ln2b + 128,
                                        lnfg, lnfb, wout, bout, out);
}

// Round 18
// 325.264 us; speedup vs baseline: 1.2055x; 1.2055x over previous
//
#include <hip/hip_runtime.h>
#include <hip/hip_bf16.h>
#include <cstdint>
#include <cstddef>

#define EPS 1e-5f
#define BB 4096
#define TT 64
#define NBLK 2
#define MROWS (BB * TT)

typedef unsigned short ushort_t;
typedef __attribute__((ext_vector_type(8))) short short8;
typedef __attribute__((ext_vector_type(4))) float floatx4;

__device__ __forceinline__ ushort_t f2b(float f) {
    __hip_bfloat16 h = __float2bfloat16(f);
    return *reinterpret_cast<ushort_t*>(&h);
}
__device__ __forceinline__ float tanh_fast(float z) {
    return 1.f - 2.f / (__expf(2.f * z) + 1.f);
}
// v_rcp_f32: ~1ulp fp32 error (2^-22) — used ONLY in the scan nonlinearity.
__device__ __forceinline__ float rcp_f(float x) {
    return __builtin_amdgcn_rcpf(x);
}
// LDS-only barrier: omits vmcnt drain on purpose.
__device__ __forceinline__ void lds_barrier() {
    asm volatile("s_waitcnt lgkmcnt(0)\n\ts_barrier" ::: "memory");
}

// DPP row_ror cyclic-add reduction over 16 lanes (pure VALU; r4-proven).
template <int CTRL>
__device__ __forceinline__ float ror_add(float v) {
    int r = __builtin_amdgcn_update_dpp(
        0, __builtin_bit_cast(int, v), CTRL, 0xf, 0xf, false);
    return v + __builtin_bit_cast(float, r);
}
__device__ __forceinline__ float red16(float v) {
    v = ror_add<0x121>(v);  // ror 1
    v = ror_add<0x122>(v);  // ror 2
    v = ror_add<0x124>(v);  // ror 4
    v = ror_add<0x128>(v);  // ror 8
    return v;
}

// ---------------- all weight converts in one launch ----------------
// r22: source-linear indexing — reads fully coalesced.
__global__ __launch_bounds__(256) void k_cvtall(
    const float* __restrict__ Wg, const float* __restrict__ W1,
    const float* __restrict__ W2, ushort_t* __restrict__ Wgt,
    ushort_t* __restrict__ W1t, ushort_t* __restrict__ W2t) {
    int idx = blockIdx.x * 256 + threadIdx.x;
    if (idx < 2 * 512 * 128) {
        int blk = idx >> 16, r = idx & 65535;
        int k = r >> 9, n = r & 511;
        Wgt[(size_t)blk * 65536 + n * 128 + k] = f2b(Wg[idx]);
    } else if (idx < 2 * 512 * 128 + 2 * 128 * 128) {
        int i2 = idx - 2 * 512 * 128;
        int blk = i2 >> 14, r = i2 & 16383;
        int k = r >> 7, n = r & 127;
        W1t[(size_t)blk * 16384 + n * 128 + k] = f2b(W1[i2]);
    } else {
        int i2 = idx - (2 * 512 * 128 + 2 * 128 * 128);
        int blk = i2 >> 14, r = i2 & 16383;
        int k = r >> 7, n = r & 127;
        W2t[(size_t)blk * 16384 + n * 128 + k] = f2b(W2[i2]);
    }
}

// ---------------- producer/consumer fused gate-GEMM + per-head sLSTM scan ----------------
// r16-verbatim (harness-verified 330us / absmax 0.03125). Do not touch.
template <bool EMBED, bool LASTONLY>
__global__ __launch_bounds__(512, 2) void k_gslstm(
    float* __restrict__ h, const float* __restrict__ x,
    const float* __restrict__ w_in, const float* __restrict__ b_in,
    const ushort_t* __restrict__ Wgt, const float* __restrict__ bg,
    const float* __restrict__ Rg,
    const float* __restrict__ ln1g, const float* __restrict__ ln1b,
    const float* __restrict__ gng, const float* __restrict__ gnb) {
    __shared__ float xg_ring[2][512][16];      // 65536 B (rotated cols)
    __shared__ ushort_t Afrag[2][16][136];     // 8704 B, LN1 output bf16 [m][k]
    __shared__ ushort_t tpose[4][16][40];      // 5120 B

    const int tid = threadIdx.x;
    const int lane = tid & 63;
    const int wave = tid >> 6;   // 0..7
    const int q = lane >> 4;     // 0..3
    const int ml = lane & 15;
    const int b0 = blockIdx.x * 16;
    const int xc = ((q + (ml >> 1)) & 3) * 4;  // rotated xg column

    if (wave < 4) {
        // ================== PRODUCER ==================
        const int p = wave;
        const int row = p * 4 + q;
        short8 WB[4][8];
#pragma unroll
        for (int ks = 0; ks < 4; ++ks)
#pragma unroll
            for (int s = 0; s < 8; ++s)
                WB[ks][s] = *(const short8*)(Wgt +
                    ((size_t)(p * 128 + s * 16 + ml) * 128 + ks * 32 + q * 8));
        float biasv[8];
#pragma unroll
        for (int s = 0; s < 8; ++s) biasv[s] = bg[p * 128 + s * 16 + ml];

        const float4 Lg0 = *(const float4*)(ln1g + ml * 8);
        const float4 Lg1 = *(const float4*)(ln1g + ml * 8 + 4);
        const float4 Lb0 = *(const float4*)(ln1b + ml * 8);
        const float4 Lb1 = *(const float4*)(ln1b + ml * 8 + 4);
        float4 W00{}, W01{}, W10{}, W11{}, W20{}, W21{}, BE0{}, BE1{};
        if (EMBED) {
            W00 = *(const float4*)(w_in + 0 * 128 + ml * 8);
            W01 = *(const float4*)(w_in + 0 * 128 + ml * 8 + 4);
            W10 = *(const float4*)(w_in + 1 * 128 + ml * 8);
            W11 = *(const float4*)(w_in + 1 * 128 + ml * 8 + 4);
            W20 = *(const float4*)(w_in + 2 * 128 + ml * 8);
            W21 = *(const float4*)(w_in + 2 * 128 + ml * 8 + 4);
            BE0 = *(const float4*)(b_in + ml * 8);
            BE1 = *(const float4*)(b_in + ml * 8 + 4);
        }

        auto issue_in = [&](int tt, float4& A, float4& B) {
            const float4* hp =
                (const float4*)(h + ((size_t)(b0 + row) * TT + tt) * 128 + ml * 8);
            A = hp[0]; B = hp[1];
        };
        auto issue_x = [&](int tt, float& x0, float& x1, float& x2) {
            const float* xp = x + ((size_t)(b0 + row) * TT + tt) * 3;
            x0 = xp[0]; x1 = xp[1]; x2 = xp[2];
        };
        auto embed_v = [&](float x0, float x1, float x2, float* v) {
            const float w0[8] = {W00.x, W00.y, W00.z, W00.w, W01.x, W01.y, W01.z, W01.w};
            const float w1[8] = {W10.x, W10.y, W10.z, W10.w, W11.x, W11.y, W11.z, W11.w};
            const float w2[8] = {W20.x, W20.y, W20.z, W20.w, W21.x, W21.y, W21.z, W21.w};
            const float be[8] = {BE0.x, BE0.y, BE0.z, BE0.w, BE1.x, BE1.y, BE1.z, BE1.w};
#pragma unroll
            for (int j = 0; j < 8; ++j)
                v[j] = x0 * w0[j] + x1 * w1[j] + x2 * w2[j] + be[j];
        };
        auto ln_stage = [&](const float* v, int aslot) {
            float s = 0.f, ss = 0.f;
#pragma unroll
            for (int j = 0; j < 8; ++j) { s += v[j]; ss += v[j] * v[j]; }
            s = red16(s);
            ss = red16(ss);
            float mu = s * (1.f / 128.f);
            float rstd = rsqrtf(ss * (1.f / 128.f) - mu * mu + EPS);
            const float gg[8] = {Lg0.x, Lg0.y, Lg0.z, Lg0.w, Lg1.x, Lg1.y, Lg1.z, Lg1.w};
            const float bbv[8] = {Lb0.x, Lb0.y, Lb0.z, Lb0.w, Lb1.x, Lb1.y, Lb1.z, Lb1.w};
            ushort_t pk[8];
#pragma unroll
            for (int j = 0; j < 8; ++j)
                pk[j] = f2b((v[j] - mu) * rstd * gg[j] + bbv[j]);
            *(short8*)&Afrag[aslot][row][ml * 8] = *(const short8*)pk;
        };
        auto gemm_stage = [&](int slot) {
            short8 af[4];
#pragma unroll
            for (int ks = 0; ks < 4; ++ks)
                af[ks] = *(const short8*)&Afrag[slot][ml][ks * 32 + q * 8];
            floatx4 acc[8];
#pragma unroll
            for (int s = 0; s < 8; ++s) {
                float b = biasv[s];
                acc[s] = (floatx4){b, b, b, b};
            }
#pragma unroll
            for (int ks = 0; ks < 4; ++ks)
#pragma unroll
                for (int s = 0; s < 8; ++s)
                    acc[s] = __builtin_amdgcn_mfma_f32_16x16x32_bf16(
                        af[ks], WB[ks][s], acc[s], 0, 0, 0);
#pragma unroll
            for (int s = 0; s < 8; ++s)
                *(floatx4*)&xg_ring[slot][p * 128 + s * 16 + ml][xc] = acc[s];
        };

        float4 pA0, pA1, pB0, pB1;
        float px0 = 0.f, px1 = 0.f, px2 = 0.f, qx0 = 0.f, qx1 = 0.f, qx2 = 0.f;
        {
            float v[8];
            if (EMBED) {
                float a0, a1, a2, d0, d1, d2v;
                issue_x(0, a0, a1, a2);
                issue_x(1, d0, d1, d2v);
                issue_x(2, px0, px1, px2);
                embed_v(a0, a1, a2, v);  ln_stage(v, 0);
                embed_v(d0, d1, d2v, v); ln_stage(v, 1);
            } else {
                float4 a0, a1, d0, d1;
                issue_in(0, a0, a1);
                issue_in(1, d0, d1);
                issue_in(2, pA0, pA1);
                *(float4*)v = a0; *(float4*)(v + 4) = a1; ln_stage(v, 0);
                *(float4*)v = d0; *(float4*)(v + 4) = d1; ln_stage(v, 1);
            }
        }
        lds_barrier();
        gemm_stage(0);  // xg(0)
        lds_barrier();

#pragma unroll 1
        for (int t = 0; t < TT; t += 2) {
            if (t + 3 < TT) {
                if (EMBED) issue_x(t + 3, qx0, qx1, qx2);
                else       issue_in(t + 3, pB0, pB1);
            }
            gemm_stage((t + 1) & 1);
            if (t + 2 < TT) {
                float v[8];
                if (EMBED) embed_v(px0, px1, px2, v);
                else { *(float4*)v = pA0; *(float4*)(v + 4) = pA1; }
                ln_stage(v, t & 1);
            }
            lds_barrier();
            if (t + 4 < TT) {
                if (EMBED) issue_x(t + 4, px0, px1, px2);
                else       issue_in(t + 4, pA0, pA1);
            }
            if (t + 2 < TT) gemm_stage(t & 1);
            if (t + 3 < TT) {
                float v[8];
                if (EMBED) embed_v(qx0, qx1, qx2, v);
                else { *(float4*)v = pB0; *(float4*)(v + 4) = pB1; }
                ln_stage(v, (t + 1) & 1);
            }
            lds_barrier();
        }
    } else {
        // ================== SCAN (one head per wave) ==================
        __builtin_amdgcn_s_setprio(1);
        const int hd = wave - 4;
        short8 RB[4][2];
#pragma unroll
        for (int g = 0; g < 4; ++g)
#pragma unroll
            for (int d2 = 0; d2 < 2; ++d2) {
                ushort_t tmp[8];
#pragma unroll
                for (int j = 0; j < 8; ++j)
                    tmp[j] = f2b(Rg[(size_t)g * 4096 + hd * 1024 +
                                    (q * 8 + j) * 32 + d2 * 16 + ml]);
                RB[g][d2] = *(const short8*)tmp;
            }
        const float gng0 = gng[hd * 32 + ml], gng1 = gng[hd * 32 + 16 + ml];
        const float gnb0 = gnb[hd * 32 + ml], gnb1 = gnb[hd * 32 + 16 + ml];
        float we[3][2], beh[2];
        if (EMBED) {
#pragma unroll
            for (int d2 = 0; d2 < 2; ++d2) {
#pragma unroll
                for (int c = 0; c < 3; ++c)
                    we[c][d2] = w_in[c * 128 + hd * 32 + d2 * 16 + ml];
                beh[d2] = b_in[hd * 32 + d2 * 16 + ml];
            }
        }
        float cst[8], nst[8], mst[8];
#pragma unroll
        for (int i = 0; i < 8; ++i) { cst[i] = 0.f; nst[i] = 0.f; mst[i] = 0.f; }
        {
            ushort_t* tp = &tpose[hd][0][0];
            for (int i = lane; i < 16 * 40; i += 64) tp[i] = 0;
        }

        auto scan_iter = [&](int t) {
            const bool doGN = (!LASTONLY || t == TT - 1);
            float xv[4][3];    // EMBED path
            float hg[4][2];    // global-h path (LASTONLY)
            if (doGN) {
                if (EMBED) {
#pragma unroll
                    for (int r = 0; r < 4; ++r) {
                        const float* xp =
                            x + ((size_t)(b0 + q * 4 + r) * TT + t) * 3;
                        xv[r][0] = xp[0]; xv[r][1] = xp[1]; xv[r][2] = xp[2];
                    }
                } else {
#pragma unroll
                    for (int r = 0; r < 4; ++r)
#pragma unroll
                        for (int d2 = 0; d2 < 2; ++d2)
                            hg[r][d2] = h[((size_t)(b0 + q * 4 + r) * TT + t) * 128 +
                                          hd * 32 + d2 * 16 + ml];
                }
            }
            short8 h8 = *(const short8*)&tpose[hd][ml][q * 8];
            floatx4 acc[4][2];
#pragma unroll
            for (int g = 0; g < 4; ++g)
#pragma unroll
                for (int d2 = 0; d2 < 2; ++d2)
                    acc[g][d2] = *(const floatx4*)
                        &xg_ring[t & 1][g * 128 + hd * 32 + d2 * 16 + ml][xc];
#pragma unroll
            for (int g = 0; g < 4; ++g)
#pragma unroll
                for (int d2 = 0; d2 < 2; ++d2)
                    acc[g][d2] = __builtin_amdgcn_mfma_f32_16x16x32_bf16(
                        h8, RB[g][d2], acc[g][d2], 0, 0, 0);
            float hv[2][4];
#pragma unroll
            for (int d2 = 0; d2 < 2; ++d2)
#pragma unroll
                for (int r = 0; r < 4; ++r) {
                    const int si = d2 * 4 + r;
                    float it = acc[0][d2][r], ft = acc[1][d2][r];
                    float zt = acc[2][d2][r], ot = acc[3][d2][r];
                    float mn = fmaxf(ft + mst[si], it);
                    float iv = __expf(it - mn);
                    float fv = __expf(ft + mst[si] - mn);
                    float e2 = __expf(2.f * zt);
                    float th = 1.f - 2.f * rcp_f(e2 + 1.f);
                    float cn = fv * cst[si] + iv * th;
                    float nn = fv * nst[si] + iv;
                    float eo = __expf(-ot);
                    hv[d2][r] = cn * rcp_f(nn + nn * eo);
                    cst[si] = cn; nst[si] = nn; mst[si] = mn;
                }
#pragma unroll
            for (int d2 = 0; d2 < 2; ++d2)
#pragma unroll
                for (int r = 0; r < 4; ++r)
                    tpose[hd][q * 4 + r][d2 * 16 + ml] = f2b(hv[d2][r]);
            if (doGN) {
                float hinv[4][2];
#pragma unroll
                for (int r = 0; r < 4; ++r)
#pragma unroll
                    for (int d2 = 0; d2 < 2; ++d2) {
                        if (EMBED)
                            hinv[r][d2] = xv[r][0] * we[0][d2] +
                                          xv[r][1] * we[1][d2] +
                                          xv[r][2] * we[2][d2] + beh[d2];
                        else
                            hinv[r][d2] = hg[r][d2];
                    }
                float s[4], ss[4];
#pragma unroll
                for (int r = 0; r < 4; ++r) {
                    s[r] = hv[0][r] + hv[1][r];
                    ss[r] = hv[0][r] * hv[0][r] + hv[1][r] * hv[1][r];
                }
#pragma unroll
                for (int r = 0; r < 4; ++r) {
                    s[r] = red16(s[r]);
                    ss[r] = red16(ss[r]);
                }
#pragma unroll
                for (int r = 0; r < 4; ++r) {
                    float mu = s[r] * (1.f / 32.f);
                    float rstd = rsqrtf(ss[r] * (1.f / 32.f) - mu * mu + EPS);
#pragma unroll
                    for (int d2 = 0; d2 < 2; ++d2) {
                        float gv = d2 ? gng1 : gng0;
                        float bv = d2 ? gnb1 : gnb0;
                        h[((size_t)(b0 + q * 4 + r) * TT + t) * 128 +
                          hd * 32 + d2 * 16 + ml] =
                            hinv[r][d2] + (hv[d2][r] - mu) * rstd * gv + bv;
                    }
                }
            }
        };

        lds_barrier();
        lds_barrier();
#pragma unroll 1
        for (int t = 0; t < TT; t += 2) {
            scan_iter(t);
            lds_barrier();
            scan_iter(t + 1);
            lds_barrier();
        }
    }
}

// ---------------- streaming pipelined FFN: h += gelu(LN2(h) @ W1) @ W2 ----------------
// r16 shape (NT=8, 3 wgs/CU, separate Hraw, 4 barriers/tile) + W2B hoisted out
// of the tile loop (loop-invariant; joins W1B). Same values, same barriers.
template <int NT>
__global__ __launch_bounds__(256, 3) void k_ffn_pipe(
    float* __restrict__ h, const ushort_t* __restrict__ W1t,
    const ushort_t* __restrict__ W2t,
    const float* __restrict__ lng, const float* __restrict__ lnb) {
    __shared__ float Hraw[32][132];                    // 16896 B
    __shared__ ushort_t T1[32][136];                   // 8704 B
    __shared__ __align__(16) char Ubuf[32 * 132 * 4];  // union: As bf16 / T2 f32
    auto As = (ushort_t(*)[136])Ubuf;
    auto T2 = (float(*)[132])Ubuf;

    int tid = threadIdx.x;
    int lane = tid & 63, wave = tid >> 6;
    int q = lane >> 4, ml = lane & 15;
    int wn = wave * 32;
    int r = tid >> 3, qd = tid & 7;
    int hi = lane >> 5, lo = lane & 31;
    size_t base = (size_t)blockIdx.x * (32 * NT);

    short8 W1B[2][4], W2B[2][4];
#pragma unroll
    for (int jn = 0; jn < 2; ++jn)
#pragma unroll
        for (int ks = 0; ks < 4; ++ks) {
            W1B[jn][ks] = *(const short8*)(W1t +
                ((size_t)(wn + jn * 16 + ml) * 128 + ks * 32 + q * 8));
            W2B[jn][ks] = *(const short8*)(W2t +
                ((size_t)(wn + jn * 16 + ml) * 128 + ks * 32 + q * 8));
        }

    float4 cur[4], nxt[4];
#pragma unroll
    for (int k = 0; k < 4; ++k)
        cur[k] = *(const float4*)(h + (base + wave * 8 + 2 * k + hi) * 128 + lo * 4);

#pragma unroll 1
    for (int it = 0; it < NT; ++it) {
#pragma unroll
        for (int k = 0; k < 4; ++k)
            *(float4*)&Hraw[wave * 8 + 2 * k + hi][lo * 4] = cur[k];
        if (it + 1 < NT) {
#pragma unroll
            for (int k = 0; k < 4; ++k)
                nxt[k] = *(const float4*)(h +
                    (base + (it + 1) * 32 + wave * 8 + 2 * k + hi) * 128 + lo * 4);
        }
        lds_barrier();  // b0

        float4 hv[4];
#pragma unroll
        for (int k = 0; k < 4; ++k)
            hv[k] = *(const float4*)&Hraw[r][qd * 16 + k * 4];
        float s = 0.f, ss = 0.f;
#pragma unroll
        for (int k = 0; k < 4; ++k) {
            float4 v = hv[k];
            s += v.x + v.y + v.z + v.w;
            ss += v.x * v.x + v.y * v.y + v.z * v.z + v.w * v.w;
        }
        s += __shfl_xor(s, 1); ss += __shfl_xor(ss, 1);
        s += __shfl_xor(s, 2); ss += __shfl_xor(ss, 2);
        s += __shfl_xor(s, 4); ss += __shfl_xor(ss, 4);
        float mu = s * (1.f / 128.f);
        float rstd = rsqrtf(ss * (1.f / 128.f) - mu * mu + EPS);
#pragma unroll
        for (int kk = 0; kk < 2; ++kk) {
            float4 a = hv[2 * kk];
            float4 b = hv[2 * kk + 1];
            int c0 = qd * 16 + kk * 8;
            float4 g0 = *(const float4*)(lng + c0);
            float4 g1 = *(const float4*)(lng + c0 + 4);
            float4 b0 = *(const float4*)(lnb + c0);
            float4 b1 = *(const float4*)(lnb + c0 + 4);
            ushort_t p[8];
            p[0] = f2b((a.x - mu) * rstd * g0.x + b0.x);
            p[1] = f2b((a.y - mu) * rstd * g0.y + b0.y);
            p[2] = f2b((a.z - mu) * rstd * g0.z + b0.z);
            p[3] = f2b((a.w - mu) * rstd * g0.w + b0.w);
            p[4] = f2b((b.x - mu) * rstd * g1.x + b1.x);
            p[5] = f2b((b.y - mu) * rstd * g1.y + b1.y);
            p[6] = f2b((b.z - mu) * rstd * g1.z + b1.z);
            p[7] = f2b((b.w - mu) * rstd * g1.w + b1.w);
            *(short8*)&As[r][c0] = *(const short8*)p;
        }
        lds_barrier();  // b1

        floatx4 acc[2][2];
#pragma unroll
        for (int i = 0; i < 2; ++i)
#pragma unroll
            for (int j = 0; j < 2; ++j) acc[i][j] = (floatx4)0.f;
#pragma unroll
        for (int ks = 0; ks < 4; ++ks) {
            short8 af[2];
#pragma unroll
            for (int im = 0; im < 2; ++im)
                af[im] = *(const short8*)&As[im * 16 + ml][ks * 32 + q * 8];
#pragma unroll
            for (int im = 0; im < 2; ++im)
#pragma unroll
                for (int jn = 0; jn < 2; ++jn)
                    acc[im][jn] = __builtin_amdgcn_mfma_f32_16x16x32_bf16(
                        af[im], W1B[jn][ks], acc[im][jn], 0, 0, 0);
        }
#pragma unroll
        for (int im = 0; im < 2; ++im)
#pragma unroll
            for (int jn = 0; jn < 2; ++jn)
#pragma unroll
                for (int rr = 0; rr < 4; ++rr) {
                    float v = acc[im][jn][rr];
                    float u = 0.7978845608028654f * (v + 0.044715f * v * v * v);
                    float gv = 0.5f * v * (1.f + tanh_fast(u));
                    T1[im * 16 + q * 4 + rr][wn + jn * 16 + ml] = f2b(gv);
                }
        lds_barrier();  // b2

#pragma unroll
        for (int i = 0; i < 2; ++i)
#pragma unroll
            for (int j = 0; j < 2; ++j) acc[i][j] = (floatx4)0.f;
#pragma unroll
        for (int ks = 0; ks < 4; ++ks) {
            short8 af[2];
#pragma unroll
            for (int im = 0; im < 2; ++im)
                af[im] = *(const short8*)&T1[im * 16 + ml][ks * 32 + q * 8];
#pragma unroll
            for (int im = 0; im < 2; ++im)
#pragma unroll
                for (int jn = 0; jn < 2; ++jn)
                    acc[im][jn] = __builtin_amdgcn_mfma_f32_16x16x32_bf16(
                        af[im], W2B[jn][ks], acc[im][jn], 0, 0, 0);
        }
#pragma unroll
        for (int im = 0; im < 2; ++im)
#pragma unroll
            for (int jn = 0; jn < 2; ++jn)
#pragma unroll
                for (int rr = 0; rr < 4; ++rr)
                    T2[im * 16 + q * 4 + rr][wn + jn * 16 + ml] = acc[im][jn][rr];
        lds_barrier();  // b3

#pragma unroll
        for (int k = 0; k < 4; ++k) {
            float4 t2v = *(const float4*)&T2[wave * 8 + 2 * k + hi][lo * 4];
            float4 o;
            o.x = cur[k].x + t2v.x;
            o.y = cur[k].y + t2v.y;
            o.z = cur[k].z + t2v.z;
            o.w = cur[k].w + t2v.w;
            *(float4*)(h + (base + it * 32 + wave * 8 + 2 * k + hi) * 128 + lo * 4) = o;
        }
        if (it + 1 < NT) {
#pragma unroll
            for (int k = 0; k < 4; ++k) cur[k] = nxt[k];
        }
        // next iteration's b0 provides the T2-read/As-write fence
    }
}

// ---------------- fused tail: FFN(t=T-1 rows) + final LN + matvec ----------------
// r14-verbatim (harness-verified).
__global__ __launch_bounds__(256, 6) void k_tail(
    const float* __restrict__ h, const ushort_t* __restrict__ W1t,
    const ushort_t* __restrict__ W2t,
    const float* __restrict__ lng, const float* __restrict__ lnb,
    const float* __restrict__ lnfg, const float* __restrict__ lnfb,
    const float* __restrict__ w_out, const float* __restrict__ b_out,
    float* __restrict__ out) {
    __shared__ __align__(16) char U[32 * 136 * 2 * 2];  // As+T1 (bf16) ∪ F (f32)
    auto As = (ushort_t(*)[136])U;
    auto T1 = (ushort_t(*)[136])(U + 32 * 136 * 2);
    auto F = (float(*)[136])U;
    int tid = threadIdx.x;
    int lane = tid & 63, wave = tid >> 6;
    int q = lane >> 4, ml = lane & 15;
    int wn = wave * 32;
    size_t row0 = (size_t)blockIdx.x * 32;

    short8 W1B[2][4];
#pragma unroll
    for (int jn = 0; jn < 2; ++jn)
#pragma unroll
        for (int ks = 0; ks < 4; ++ks)
            W1B[jn][ks] = *(const short8*)(W1t +
                ((size_t)(wn + jn * 16 + ml) * 128 + ks * 32 + q * 8));

    int r = tid >> 3, qd = tid & 7;
    size_t grow = (row0 + r) * TT + (TT - 1);
    const float* hrow = h + grow * 128 + qd * 16;
    float s = 0.f, ss = 0.f;
#pragma unroll
    for (int k = 0; k < 4; ++k) {
        float4 v = ((const float4*)hrow)[k];
        s += v.x + v.y + v.z + v.w;
        ss += v.x * v.x + v.y * v.y + v.z * v.z + v.w * v.w;
    }
    s += __shfl_xor(s, 1); ss += __shfl_xor(ss, 1);
    s += __shfl_xor(s, 2); ss += __shfl_xor(ss, 2);
    s += __shfl_xor(s, 4); ss += __shfl_xor(ss, 4);
    float mu = s * (1.f / 128.f);
    float rstd = rsqrtf(ss * (1.f / 128.f) - mu * mu + EPS);
#pragma unroll
    for (int kk = 0; kk < 2; ++kk) {
        float4 a = ((const float4*)hrow)[2 * kk];
        float4 b = ((const float4*)hrow)[2 * kk + 1];
        int c0 = qd * 16 + kk * 8;
        float4 g0 = *(const float4*)(lng + c0);
        float4 g1 = *(const float4*)(lng + c0 + 4);
        float4 b0 = *(const float4*)(lnb + c0);
        float4 b1 = *(const float4*)(lnb + c0 + 4);
        ushort_t p[8];
        p[0] = f2b((a.x - mu) * rstd * g0.x + b0.x);
        p[1] = f2b((a.y - mu) * rstd * g0.y + b0.y);
        p[2] = f2b((a.z - mu) * rstd * g0.z + b0.z);
        p[3] = f2b((a.w - mu) * rstd * g0.w + b0.w);
        p[4] = f2b((b.x - mu) * rstd * g1.x + b1.x);
        p[5] = f2b((b.y - mu) * rstd * g1.y + b1.y);
        p[6] = f2b((b.z - mu) * rstd * g1.z + b1.z);
        p[7] = f2b((b.w - mu) * rstd * g1.w + b1.w);
        *(short8*)&As[r][c0] = *(const short8*)p;
    }
    lds_barrier();  // b1: As ready

    floatx4 acc[2][2];
#pragma unroll
    for (int i = 0; i < 2; ++i)
#pragma unroll
        for (int j = 0; j < 2; ++j) acc[i][j] = (floatx4)0.f;
#pragma unroll
    for (int ks = 0; ks < 4; ++ks) {
        short8 af[2];
#pragma unroll
        for (int im = 0; im < 2; ++im)
            af[im] = *(const short8*)&As[im * 16 + ml][ks * 32 + q * 8];
#pragma unroll
        for (int im = 0; im < 2; ++im)
#pragma unroll
            for (int jn = 0; jn < 2; ++jn)
                acc[im][jn] = __builtin_amdgcn_mfma_f32_16x16x32_bf16(
                    af[im], W1B[jn][ks], acc[im][jn], 0, 0, 0);
    }
#pragma unroll
    for (int im = 0; im < 2; ++im)
#pragma unroll
        for (int jn = 0; jn < 2; ++jn)
#pragma unroll
            for (int rr = 0; rr < 4; ++rr) {
                float v = acc[im][jn][rr];
                float u = 0.7978845608028654f * (v + 0.044715f * v * v * v);
                float gv = 0.5f * v * (1.f + tanh_fast(u));
                T1[im * 16 + q * 4 + rr][wn + jn * 16 + ml] = f2b(gv);
            }
    short8 W2B[2][4];
#pragma unroll
    for (int jn = 0; jn < 2; ++jn)
#pragma unroll
        for (int ks = 0; ks < 4; ++ks)
            W2B[jn][ks] = *(const short8*)(W2t +
                ((size_t)(wn + jn * 16 + ml) * 128 + ks * 32 + q * 8));
    lds_barrier();  // b2: T1 ready (As dead hereafter)

    float rres[2][2][4];
#pragma unroll
    for (int im = 0; im < 2; ++im)
#pragma unroll
        for (int jn = 0; jn < 2; ++jn)
#pragma unroll
            for (int rr = 0; rr < 4; ++rr) {
                int rloc = im * 16 + q * 4 + rr;
                rres[im][jn][rr] = h[((row0 + rloc) * TT + (TT - 1)) * 128 +
                                     wn + jn * 16 + ml];
            }
#pragma unroll
    for (int i = 0; i < 2; ++i)
#pragma unroll
        for (int j = 0; j < 2; ++j) acc[i][j] = (floatx4)0.f;
#pragma unroll
    for (int ks = 0; ks < 4; ++ks) {
        short8 af[2];
#pragma unroll
        for (int im = 0; im < 2; ++im)
            af[im] = *(const short8*)&T1[im * 16 + ml][ks * 32 + q * 8];
#pragma unroll
        for (int im = 0; im < 2; ++im)
#pragma unroll
            for (int jn = 0; jn < 2; ++jn)
                acc[im][jn] = __builtin_amdgcn_mfma_f32_16x16x32_bf16(
                    af[im], W2B[jn][ks], acc[im][jn], 0, 0, 0);
    }
    lds_barrier();  // b3: T1 consumed -> U reusable as F
#pragma unroll
    for (int im = 0; im < 2; ++im)
#pragma unroll
        for (int jn = 0; jn < 2; ++jn)
#pragma unroll
            for (int rr = 0; rr < 4; ++rr) {
                int rloc = im * 16 + q * 4 + rr;
                F[rloc][wn + jn * 16 + ml] = rres[im][jn][rr] + acc[im][jn][rr];
            }
    lds_barrier();  // b4: F ready

    float4 fv[4];
#pragma unroll
    for (int k = 0; k < 4; ++k)
        fv[k] = *(const float4*)&F[r][qd * 16 + k * 4];
    float s2 = 0.f, ss2 = 0.f;
#pragma unroll
    for (int k = 0; k < 4; ++k) {
        float4 v = fv[k];
        s2 += v.x + v.y + v.z + v.w;
        ss2 += v.x * v.x + v.y * v.y + v.z * v.z + v.w * v.w;
    }
    s2 += __shfl_xor(s2, 1); ss2 += __shfl_xor(ss2, 1);
    s2 += __shfl_xor(s2, 2); ss2 += __shfl_xor(ss2, 2);
    s2 += __shfl_xor(s2, 4); ss2 += __shfl_xor(ss2, 4);
    float mu2 = s2 * (1.f / 128.f);
    float rstd2 = rsqrtf(ss2 * (1.f / 128.f) - mu2 * mu2 + EPS);
    float dot = 0.f;
#pragma unroll
    for (int k = 0; k < 4; ++k) {
        int c0 = qd * 16 + k * 4;
        float4 g = *(const float4*)(lnfg + c0);
        float4 bb = *(const float4*)(lnfb + c0);
        float4 w = *(const float4*)(w_out + c0);
        dot += ((fv[k].x - mu2) * rstd2 * g.x + bb.x) * w.x +
               ((fv[k].y - mu2) * rstd2 * g.y + bb.y) * w.y +
               ((fv[k].z - mu2) * rstd2 * g.z + bb.z) * w.z +
               ((fv[k].w - mu2) * rstd2 * g.w + bb.w) * w.w;
    }
    dot += __shfl_xor(dot, 1);
    dot += __shfl_xor(dot, 2);
    dot += __shfl_xor(dot, 4);
    if (qd == 0) out[row0 + r] = dot + b_out[0];
}

extern "C" void kernel_launch(void* const* d_in, const int* in_sizes, int n_in,
                              void* d_out, int out_size, void* d_ws, size_t ws_size,
                              hipStream_t stream) {
    const float* x    = (const float*)d_in[0];
    const float* w_in = (const float*)d_in[1];
    const float* b_in = (const float*)d_in[2];
    const float* ln1g = (const float*)d_in[3];
    const float* ln1b = (const float*)d_in[4];
    const float* Wg   = (const float*)d_in[5];
    const float* bg   = (const float*)d_in[6];
    const float* Rg   = (const float*)d_in[7];
    const float* gng  = (const float*)d_in[8];
    const float* gnb  = (const float*)d_in[9];
    const float* ln2g = (const float*)d_in[10];
    const float* ln2b = (const float*)d_in[11];
    const float* W1   = (const float*)d_in[12];
    const float* W2   = (const float*)d_in[13];
    const float* lnfg = (const float*)d_in[14];
    const float* lnfb = (const float*)d_in[15];
    const float* wout = (const float*)d_in[16];
    const float* bout = (const float*)d_in[17];
    float* out = (float*)d_out;

    float* h = (float*)d_ws;
    ushort_t* Wgt = (ushort_t*)(h + (size_t)MROWS * 128);
    ushort_t* W1t = Wgt + 2 * 512 * 128;
    ushort_t* W2t = W1t + 2 * 128 * 128;

    k_cvtall<<<(2 * 512 * 128 + 4 * 128 * 128) / 256, 256, 0, stream>>>(
        Wg, W1, W2, Wgt, W1t, W2t);

    k_gslstm<true, false><<<BB / 16, 512, 0, stream>>>(
        h, x, w_in, b_in, Wgt, bg, Rg, ln1g, ln1b, gng, gnb);
    k_ffn_pipe<8><<<MROWS / 256, 256, 0, stream>>>(h, W1t, W2t, ln2g, ln2b);
    k_gslstm<false, true><<<BB / 16, 512, 0, stream>>>(
        h, nullptr, nullptr, nullptr, Wgt + (size_t)512 * 128, bg + 512,
        Rg + (size_t)16384, ln1g + 128, ln1b + 128, gng + 128, gnb + 128);
    k_tail<<<BB / 32, 256, 0, stream>>>(h, W1t + 16384, W2t + 16384,
                                        ln2g + 128, ln2b + 128,
                                        lnfg, lnfb, wout, bout, out);
}